// Round 11
// baseline (12766.134 us; speedup 1.0000x reference)
//
#include <hip/hip_runtime.h>
#include <hip/hip_bf16.h>
#include <cstdint>
#include <cstddef>

// Problem constants
#define Bn 64
#define Pn 196
#define ENCn 2048
#define DECn 512
#define ATTn 512
#define En 300
#define Vn 30000
#define Tn 21
#define STEPSn 20
#define Gn 2048        // 4*DEC gate width
#define NBLK 256       // step-kernel grid: 1 block/CU (R6-proven safe for grid barrier)

// ---- workspace layout (float offsets) ----
#define WS_ENCPROJ ((size_t)0)                            // [64*196][512]; reused post-loop for Ah/Al
#define WS_WT    (WS_ENCPROJ + (size_t)Bn*Pn*ATTn)        // [2348][2048] = W_ih^T
#define WS_CTX   (WS_WT + (size_t)(En+ENCn)*Gn)           // [64][2048] (also mean_f pre-loop)
#define WS_H0    (WS_CTX + (size_t)Bn*ENCn)               // [64][512]
#define WS_C     (WS_H0 + (size_t)Bn*DECn)                // [64][512]
#define WS_HALL  (WS_C + (size_t)Bn*DECn)                 // [64][20][512] row r=b*20+t
#define WS_BAR   (WS_HALL + (size_t)Bn*STEPSn*DECn)       // 2 unsigned (cnt, gen)

// ---- output layout (float offsets into d_out) ----
#define OUT_ALPHAS ((size_t)Bn*STEPSn*Vn)                 // 38,400,000
#define OUT_CAPT   (OUT_ALPHAS + (size_t)Bn*STEPSn*Pn)
#define OUT_SEQ    (OUT_CAPT + (size_t)Bn*Tn)
// NOTE: during the loop, d_out[0 .. 12.85M) floats (logits region) hold the
// bf16 feature copy; overwritten by the final GEMM.

typedef __attribute__((ext_vector_type(8))) short short8;
typedef __attribute__((ext_vector_type(4))) short short4v;
typedef __attribute__((ext_vector_type(4))) float f32x4;

static __device__ __forceinline__ unsigned short f2bf(float f) {
    unsigned u = __float_as_uint(f);
    return (unsigned short)((u + 0x7FFFu + ((u >> 16) & 1u)) >> 16);
}

// ============ enc_proj via split-bf16 MFMA (verbatim R8) ============
__global__ __launch_bounds__(256) void k_encproj_mfma(
        const float* __restrict__ A,
        const float* __restrict__ B,
        const float* __restrict__ bias,
        float* __restrict__ C) {
    __shared__ short Ah[128][40];
    __shared__ short Al[128][40];
    __shared__ short Bh[128][40];
    __shared__ short Bl[128][40];
    int m0 = blockIdx.x * 128, n0 = blockIdx.y * 128;
    int tid = threadIdx.x;
    int w = tid >> 6, l = tid & 63;
    int lr = l & 15, lk = (l >> 4) * 8;

    f32x4 acc[2][8];
    #pragma unroll
    for (int mt = 0; mt < 2; ++mt)
        #pragma unroll
        for (int nt = 0; nt < 8; ++nt) acc[mt][nt] = (f32x4){0.f, 0.f, 0.f, 0.f};

    for (int k0 = 0; k0 < ENCn; k0 += 32) {
        __syncthreads();
        #pragma unroll
        for (int i = 0; i < 2; ++i) {
            int q = tid + i * 256;
            int r = q >> 2, c8 = (q & 3) * 8;
            const float* src = A + (size_t)(m0 + r) * ENCn + k0 + c8;
            float4 v0 = *(const float4*)src;
            float4 v1 = *(const float4*)(src + 4);
            float vv[8] = {v0.x, v0.y, v0.z, v0.w, v1.x, v1.y, v1.z, v1.w};
            short8 h8, l8;
            #pragma unroll
            for (int j = 0; j < 8; ++j) {
                unsigned short hi = f2bf(vv[j]);
                float rem = vv[j] - __uint_as_float((unsigned)hi << 16);
                h8[j] = (short)hi;
                l8[j] = (short)f2bf(rem);
            }
            *(short8*)&Ah[r][c8] = h8;
            *(short8*)&Al[r][c8] = l8;
        }
        #pragma unroll
        for (int i = 0; i < 2; ++i) {
            int q = tid + i * 256;
            int n = q & 127, kc = (q >> 7) * 8;
            float vv[8];
            #pragma unroll
            for (int j = 0; j < 8; ++j)
                vv[j] = B[(size_t)(k0 + kc + j) * ATTn + n0 + n];
            short8 h8, l8;
            #pragma unroll
            for (int j = 0; j < 8; ++j) {
                unsigned short hi = f2bf(vv[j]);
                float rem = vv[j] - __uint_as_float((unsigned)hi << 16);
                h8[j] = (short)hi;
                l8[j] = (short)f2bf(rem);
            }
            *(short8*)&Bh[n][kc] = h8;
            *(short8*)&Bl[n][kc] = l8;
        }
        __syncthreads();
        short8 ah[2], al2[2];
        #pragma unroll
        for (int mt = 0; mt < 2; ++mt) {
            int row = w * 32 + mt * 16 + lr;
            ah[mt]  = *(const short8*)&Ah[row][lk];
            al2[mt] = *(const short8*)&Al[row][lk];
        }
        #pragma unroll
        for (int nt = 0; nt < 8; ++nt) {
            short8 bh = *(const short8*)&Bh[nt * 16 + lr][lk];
            short8 bl = *(const short8*)&Bl[nt * 16 + lr][lk];
            #pragma unroll
            for (int mt = 0; mt < 2; ++mt) {
                acc[mt][nt] = __builtin_amdgcn_mfma_f32_16x16x32_bf16(ah[mt], bh, acc[mt][nt], 0, 0, 0);
                acc[mt][nt] = __builtin_amdgcn_mfma_f32_16x16x32_bf16(ah[mt], bl, acc[mt][nt], 0, 0, 0);
                acc[mt][nt] = __builtin_amdgcn_mfma_f32_16x16x32_bf16(al2[mt], bh, acc[mt][nt], 0, 0, 0);
            }
        }
    }
    #pragma unroll
    for (int mt = 0; mt < 2; ++mt) {
        #pragma unroll
        for (int nt = 0; nt < 8; ++nt) {
            int n = n0 + nt * 16 + lr;
            float bv = bias[n];
            #pragma unroll
            for (int r = 0; r < 4; ++r) {
                int m = m0 + w * 32 + mt * 16 + (l >> 4) * 4 + r;
                C[(size_t)m * ATTn + n] = acc[mt][nt][r] + bv;
            }
        }
    }
}

// ================= small precompute kernels =================

__global__ __launch_bounds__(256) void k_feat2bf(const float* __restrict__ feat,
                                                 unsigned short* __restrict__ outbf) {
    size_t idx = ((size_t)blockIdx.x * 256 + threadIdx.x) * 8;
    float4 v0 = *(const float4*)(feat + idx);
    float4 v1 = *(const float4*)(feat + idx + 4);
    float vv[8] = {v0.x, v0.y, v0.z, v0.w, v1.x, v1.y, v1.z, v1.w};
    short8 o;
    #pragma unroll
    for (int j = 0; j < 8; ++j) o[j] = (short)f2bf(vv[j]);
    *(short8*)(outbf + idx) = o;
}

__global__ __launch_bounds__(256) void k_mean(const float* __restrict__ feat,
                                              float* __restrict__ mean_f) {
    int b = blockIdx.x;
    int e = blockIdx.y * 256 + threadIdx.x;
    const float* fb = feat + (size_t)b * Pn * ENCn + e;
    float s = 0.f;
    #pragma unroll 4
    for (int p = 0; p < Pn; ++p) s += fb[(size_t)p * ENCn];
    mean_f[(size_t)b * ENCn + e] = s * (1.0f / (float)Pn);
}

__global__ __launch_bounds__(256) void k_init_state(
        const float* __restrict__ mf,
        const float* __restrict__ Wh, const float* __restrict__ bh,
        const float* __restrict__ Wc, const float* __restrict__ bc,
        float* __restrict__ h, float* __restrict__ c) {
    int n = blockIdx.x * 256 + threadIdx.x;
    int b0 = blockIdx.y * 4;
    float ah[4], ac[4];
    float bhv = bh[n], bcv = bc[n];
    #pragma unroll
    for (int j = 0; j < 4; ++j) { ah[j] = bhv; ac[j] = bcv; }
    for (int k = 0; k < ENCn; ++k) {
        float wh = Wh[(size_t)k * DECn + n];
        float wc = Wc[(size_t)k * DECn + n];
        #pragma unroll
        for (int j = 0; j < 4; ++j) {
            float a = mf[(size_t)(b0 + j) * ENCn + k];
            ah[j] += a * wh;
            ac[j] += a * wc;
        }
    }
    #pragma unroll
    for (int j = 0; j < 4; ++j) {
        h[(size_t)(b0 + j) * DECn + n] = ah[j];
        c[(size_t)(b0 + j) * DECn + n] = ac[j];
    }
}

__global__ __launch_bounds__(256) void k_transpose(const float* __restrict__ in,
                                                   float* __restrict__ out,
                                                   int R, int C) {
    __shared__ float tile[32][33];
    int c0 = blockIdx.x * 32, r0 = blockIdx.y * 32;
    int tx = threadIdx.x & 31, ty = threadIdx.x >> 5;
    for (int i = ty; i < 32; i += 8) {
        int r = r0 + i, cc = c0 + tx;
        tile[i][tx] = (r < R && cc < C) ? in[(size_t)r * C + cc] : 0.f;
    }
    __syncthreads();
    for (int i = ty; i < 32; i += 8) {
        int cc = c0 + i, r = r0 + tx;
        if (cc < C && r < R) out[(size_t)cc * R + r] = tile[tx][i];
    }
}

__global__ __launch_bounds__(256) void k_tail(const int* __restrict__ captions,
                                              const int* __restrict__ caption_len,
                                              float* __restrict__ out) {
    int i = blockIdx.x * 256 + threadIdx.x;
    if (i < Bn * Tn) {
        out[OUT_CAPT + i] = (float)captions[i];
    } else if (i < Bn * Tn + Bn) {
        int b = i - Bn * Tn;
        out[OUT_SEQ + b] = (float)(caption_len[b] - 1);
    }
}

__global__ void k_bar_init(unsigned* bar) {
    bar[0] = 0u;
    bar[1] = 0u;
}

// ================= fused per-step kernel =================
// 256 blocks (1/CU; R6-proven safe for the grid barrier). Phase bodies are
// verbatim R10 (attn on blocks 0..63; ctx/gates as 2 serial virtual tasks,
// vb = bid + half*256, with identical per-output text) -> bit-identical
// trajectory vs round 10.

static __device__ __forceinline__ void grid_bar(unsigned* cnt, unsigned* gen) {
    __syncthreads();
    if (threadIdx.x == 0) {
        unsigned g = __hip_atomic_load(gen, __ATOMIC_RELAXED, __HIP_MEMORY_SCOPE_AGENT);
        __threadfence();
        unsigned a = __hip_atomic_fetch_add(cnt, 1u, __ATOMIC_ACQ_REL, __HIP_MEMORY_SCOPE_AGENT);
        if (a == NBLK - 1) {
            __hip_atomic_store(cnt, 0u, __ATOMIC_RELAXED, __HIP_MEMORY_SCOPE_AGENT);
            __hip_atomic_store(gen, g + 1u, __ATOMIC_RELEASE, __HIP_MEMORY_SCOPE_AGENT);
        } else {
            while (__hip_atomic_load(gen, __ATOMIC_ACQUIRE, __HIP_MEMORY_SCOPE_AGENT) == g) {
                __builtin_amdgcn_s_sleep(2);
            }
        }
        __threadfence();
    }
    __syncthreads();
}

__global__ __launch_bounds__(256) void k_step(
        const float* __restrict__ enc_proj,
        const unsigned short* __restrict__ fbf,
        const float* __restrict__ WT,
        const float* __restrict__ emb,
        const int* __restrict__ captions,
        const float* __restrict__ W_dec, const float* __restrict__ b_dec,
        const float* __restrict__ W_att, const float* __restrict__ b_att,
        const float* __restrict__ b_ih, const float* __restrict__ b_hh,
        const float* __restrict__ hbase, int hstride,
        float* __restrict__ c,
        float* __restrict__ ctx,
        float* __restrict__ hall,
        float* __restrict__ alphas_out,
        unsigned* __restrict__ bar, int t) {
    __shared__ float smem[6416];
    int bid = blockIdx.x;
    int tid = threadIdx.x;

    // ---------- phase A: hdec + scores + softmax (blocks 0..63; verbatim R10 k_attn) ----------
    if (bid < Bn) {
        float* hv = smem;            // 512
        float* hs = smem + 512;      // 512
        float* wa = smem + 1024;     // 512
        float* al = smem + 1536;     // 196
        float* red = smem + 1732;    // 4
        int b = bid;
        hv[tid]       = hbase[(size_t)b * hstride + tid];
        hv[tid + 256] = hbase[(size_t)b * hstride + tid + 256];
        wa[tid]       = W_att[tid];
        wa[tid + 256] = W_att[tid + 256];
        __syncthreads();
        {
            float acc0 = b_dec[tid], acc1 = b_dec[tid + 256];
            const float* wd = W_dec + tid;
            #pragma unroll 8
            for (int k = 0; k < DECn; ++k) {
                float h = hv[k];
                acc0 += h * wd[(size_t)k * DECn];
                acc1 += h * wd[(size_t)k * DECn + 256];
            }
            hs[tid] = acc0;
            hs[tid + 256] = acc1;
        }
        __syncthreads();
        int wv = tid >> 6, lane = tid & 63;
        float batt = b_att[0];
        for (int p = wv; p < Pn; p += 4) {
            const float* ep = enc_proj + ((size_t)b * Pn + p) * ATTn;
            float s = 0.f;
            #pragma unroll 2
            for (int a = lane; a < ATTn; a += 64) {
                float v = ep[a] + hs[a];
                s += fmaxf(v, 0.f) * wa[a];
            }
            #pragma unroll
            for (int off = 32; off > 0; off >>= 1) s += __shfl_xor(s, off);
            if (lane == 0) al[p] = s + batt;
        }
        __syncthreads();
        float v = (tid < Pn) ? al[tid] : -1e30f;
        float m = v;
        #pragma unroll
        for (int off = 32; off > 0; off >>= 1) m = fmaxf(m, __shfl_xor(m, off));
        if (lane == 0) red[wv] = m;
        __syncthreads();
        float M = fmaxf(fmaxf(red[0], red[1]), fmaxf(red[2], red[3]));
        __syncthreads();
        float e = (tid < Pn) ? expf(v - M) : 0.f;
        float s = e;
        #pragma unroll
        for (int off = 32; off > 0; off >>= 1) s += __shfl_xor(s, off);
        if (lane == 0) red[wv] = s;
        __syncthreads();
        float S = red[0] + red[1] + red[2] + red[3];
        if (tid < Pn) {
            alphas_out[((size_t)b * STEPSn + t) * Pn + tid] = e / S;
        }
    }
    grid_bar(bar, bar + 1);

    // ---------- phase B: ctx from bf16 features (2 vtasks; verbatim R10 k_ctx_bf) ----------
    #pragma unroll
    for (int half = 0; half < 2; ++half) {
        int vb = bid + half * NBLK;
        float* al = smem;                                        // 196
        unsigned short* Fl = (unsigned short*)(smem + 196);      // [32][256]
        int b = vb >> 3, y = vb & 7;
        __syncthreads();   // protect smem across halves
        if (tid < Pn) al[tid] = alphas_out[((size_t)b * STEPSn + t) * Pn + tid];
        const unsigned short* fb = fbf + (size_t)b * Pn * ENCn + (size_t)y * 256;
        float acc0 = 0.f;
        int p0 = 0;
        for (int pc = 0; pc < 7; ++pc) {
            int rows = (pc < 6) ? 32 : 4;   // 196 = 6*32 + 4
            __syncthreads();
            for (int q = tid; q < rows * 32; q += 256) {
                int pr = q >> 5, c8 = (q & 31) * 8;
                *(short8*)&Fl[pr * 256 + c8] =
                    *(const short8*)&fb[(size_t)(p0 + pr) * ENCn + c8];
            }
            __syncthreads();
            #pragma unroll 4
            for (int pr = 0; pr < rows; ++pr) {
                float fv = __uint_as_float((unsigned)Fl[pr * 256 + tid] << 16);
                acc0 += al[p0 + pr] * fv;
            }
            p0 += rows;
        }
        ctx[(size_t)b * ENCn + y * 256 + tid] = acc0;
    }
    grid_bar(bar, bar + 1);

    // ---------- phase C: gates + LSTM (2 vtasks; verbatim R10 k_gates) ----------
    #pragma unroll
    for (int half = 0; half < 2; ++half) {
        int vb = bid + half * NBLK;
        float (*Ap)[516] = (float (*)[516])smem;                 // 2064
        float* Wl = smem + 2064;                                 // [64][64]
        float (*sg)[16][4] = (float (*)[16][4])(smem + 6160);    // 256
        int x = vb & 31, ybk = vb >> 5;
        int lane = tid & 63, wv = tid >> 6;
        int gate = lane >> 4, dd = lane & 15;
        int g = (gate << 9) + x * 16 + dd;
        int b0 = ybk * 4;

        float bias = b_ih[g] + b_hh[g];
        float acc0 = bias;

        const int cbase[6] = {0, 512, 1024, 1536, 2048, 2560};
        for (int ch = 0; ch < 6; ++ch) {
            int base = cbase[ch];
            int klen = (ch == 5) ? 300 : 512;
            __syncthreads();
            int qpb = klen >> 2;
            for (int q = tid; q < (qpb << 2); q += 256) {
                int bb = q / qpb;
                int kq = q - bb * qpb;
                int kg = base + kq * 4;
                int bglob = b0 + bb;
                const float* src;
                if (kg < En) src = emb + (size_t)captions[bglob * Tn + t] * En + kg;
                else if (kg < En + ENCn) src = ctx + (size_t)bglob * ENCn + (kg - En);
                else src = hbase + (size_t)bglob * hstride + (kg - En - ENCn);
                *(float4*)&Ap[bb][kq * 4] = *(const float4*)src;
            }
            for (int sub = 0; sub < klen; sub += 64) {
                int rows = (klen - sub < 64) ? (klen - sub) : 64;
                __syncthreads();
                for (int q = tid; q < rows * 16; q += 256) {
                    int kr = q >> 4, f4 = q & 15;
                    int seg = f4 >> 2, sf = f4 & 3;
                    int gg = (seg << 9) + x * 16 + sf * 4;
                    *(float4*)&Wl[kr * 64 + seg * 16 + sf * 4] =
                        *(const float4*)&WT[(size_t)(base + sub + kr) * Gn + gg];
                }
                __syncthreads();
                const float* a0p = &Ap[wv][sub];
                #pragma unroll 4
                for (int k = 0; k < rows; ++k) {
                    acc0 += Wl[k * 64 + lane] * a0p[k];
                }
            }
        }
        sg[gate][dd][wv] = acc0;
        __syncthreads();
        if (tid < 64) {
            int dl = tid & 15, bl = tid >> 4;
            float gi = sg[0][dl][bl], gf = sg[1][dl][bl];
            float gg = sg[2][dl][bl], go = sg[3][dl][bl];
            int bglob = b0 + bl, d = x * 16 + dl;
            float si = 1.f / (1.f + expf(-gi));
            float sf = 1.f / (1.f + expf(-gf));
            float so = 1.f / (1.f + expf(-go));
            size_t cidx = (size_t)bglob * DECn + d;
            float cc = sf * c[cidx] + si * tanhf(gg);
            float hh = so * tanhf(cc);
            c[cidx] = cc;
            hall[((size_t)bglob * STEPSn + t) * DECn + d] = hh;
        }
    }
}

// ================= logits via split-bf16 MFMA =================

__global__ __launch_bounds__(256) void k_splitA(const float* __restrict__ hall,
                                                short* __restrict__ Ah,
                                                short* __restrict__ Al) {
    int idx = blockIdx.x * 256 + threadIdx.x;
    size_t base = (size_t)idx * 4;
    float4 v = *(const float4*)(hall + base);
    float a[4] = {v.x, v.y, v.z, v.w};
    short4v h, l;
    #pragma unroll
    for (int j = 0; j < 4; ++j) {
        unsigned short hi = f2bf(a[j]);
        float lo = a[j] - __uint_as_float((unsigned)hi << 16);
        h[j] = (short)hi;
        l[j] = (short)f2bf(lo);
    }
    *(short4v*)(Ah + base) = h;
    *(short4v*)(Al + base) = l;
}

__global__ __launch_bounds__(512) void k_logits_mfma(const short* __restrict__ Ah,
                                                     const short* __restrict__ Al,
                                                     const float* __restrict__ W_out,
                                                     const float* __restrict__ b_out,
                                                     float* __restrict__ out) {
    __shared__ short Bh[48][520];
    __shared__ short Bl[48][520];
    int n0 = blockIdx.x * 48;
    int tid = threadIdx.x;
    for (int q = tid; q < 6144; q += 512) {
        int cq = q % 12, k = q / 12;
        const float* src = W_out + (size_t)k * Vn + n0 + cq * 4;
        float4 v = *(const float4*)src;
        float a[4] = {v.x, v.y, v.z, v.w};
        #pragma unroll
        for (int j = 0; j < 4; ++j) {
            unsigned short hi = f2bf(a[j]);
            float lo = a[j] - __uint_as_float((unsigned)hi << 16);
            Bh[cq * 4 + j][k] = (short)hi;
            Bl[cq * 4 + j][k] = (short)f2bf(lo);
        }
    }
    __syncthreads();
    int w = tid >> 6, l = tid & 63;
    int lr = l & 15, lk = (l >> 4) * 8;
    float bias[3];
    #pragma unroll
    for (int nt = 0; nt < 3; ++nt) bias[nt] = b_out[n0 + nt * 16 + lr];

    for (int chunk = 0; chunk < 10; ++chunk) {
        int m0 = chunk * 128 + w * 16;
        f32x4 acc[3];
        #pragma unroll
        for (int nt = 0; nt < 3; ++nt) acc[nt] = (f32x4){0.f, 0.f, 0.f, 0.f};
        #pragma unroll 2
        for (int ks = 0; ks < 16; ++ks) {
            int k0 = ks * 32;
            short8 ah = *(const short8*)(Ah + (size_t)(m0 + lr) * DECn + k0 + lk);
            short8 al = *(const short8*)(Al + (size_t)(m0 + lr) * DECn + k0 + lk);
            #pragma unroll
            for (int nt = 0; nt < 3; ++nt) {
                short8 bh = *(const short8*)&Bh[nt * 16 + lr][k0 + lk];
                short8 bl = *(const short8*)&Bl[nt * 16 + lr][k0 + lk];
                acc[nt] = __builtin_amdgcn_mfma_f32_16x16x32_bf16(ah, bh, acc[nt], 0, 0, 0);
                acc[nt] = __builtin_amdgcn_mfma_f32_16x16x32_bf16(ah, bl, acc[nt], 0, 0, 0);
                acc[nt] = __builtin_amdgcn_mfma_f32_16x16x32_bf16(al, bh, acc[nt], 0, 0, 0);
            }
        }
        #pragma unroll
        for (int nt = 0; nt < 3; ++nt) {
            int n = n0 + nt * 16 + lr;
            #pragma unroll
            for (int r = 0; r < 4; ++r) {
                int m = m0 + (l >> 4) * 4 + r;
                out[(size_t)m * Vn + n] = acc[nt][r] + bias[nt];
            }
        }
    }
}

// ================= launcher =================

extern "C" void kernel_launch(void* const* d_in, const int* in_sizes, int n_in,
                              void* d_out, int out_size, void* d_ws, size_t ws_size,
                              hipStream_t stream) {
    const float* features    = (const float*)d_in[0];
    const int*   captions    = (const int*)d_in[1];
    const int*   caption_len = (const int*)d_in[2];
    const float* emb         = (const float*)d_in[3];
    const float* W_enc       = (const float*)d_in[4];
    const float* b_enc       = (const float*)d_in[5];
    const float* W_dec       = (const float*)d_in[6];
    const float* b_dec       = (const float*)d_in[7];
    const float* W_att       = (const float*)d_in[8];
    const float* b_att       = (const float*)d_in[9];
    const float* W_h0        = (const float*)d_in[10];
    const float* b_h0        = (const float*)d_in[11];
    const float* W_c0        = (const float*)d_in[12];
    const float* b_c0        = (const float*)d_in[13];
    const float* W_ih        = (const float*)d_in[14];
    const float* b_ih        = (const float*)d_in[15];
    const float* W_hh        = (const float*)d_in[16];
    const float* b_hh        = (const float*)d_in[17];
    const float* W_out       = (const float*)d_in[18];
    const float* b_out       = (const float*)d_in[19];

    float* out = (float*)d_out;
    float* ws  = (float*)d_ws;

    float* ws_encproj = ws + WS_ENCPROJ;
    float* ws_WT      = ws + WS_WT;
    float* ws_ctx     = ws + WS_CTX;
    float* ws_h0      = ws + WS_H0;
    float* ws_c       = ws + WS_C;
    float* ws_hall    = ws + WS_HALL;
    unsigned* ws_bar  = (unsigned*)(ws + WS_BAR);
    short* ws_Ah      = (short*)(ws + WS_ENCPROJ);       // reuse enc_proj region post-loop
    short* ws_Al      = ws_Ah + (size_t)Bn * STEPSn * DECn;
    unsigned short* feat_bf = (unsigned short*)out;      // stash in unused logits region

    // ---- precompute ----
    k_bar_init<<<dim3(1), 1, 0, stream>>>(ws_bar);
    k_feat2bf<<<dim3(Bn * Pn * ENCn / 2048), 256, 0, stream>>>(features, feat_bf);
    k_encproj_mfma<<<dim3(Pn * Bn / 128, ATTn / 128), 256, 0, stream>>>(
        features, W_enc, b_enc, ws_encproj);
    k_mean<<<dim3(Bn, ENCn / 256), 256, 0, stream>>>(features, ws_ctx);
    k_transpose<<<dim3((En + ENCn + 31) / 32, Gn / 32), 256, 0, stream>>>(
        W_ih, ws_WT, Gn, En + ENCn);
    k_init_state<<<dim3(2, 16), 256, 0, stream>>>(ws_ctx, W_h0, b_h0, W_c0, b_c0,
                                                  ws_h0, ws_c);
    k_tail<<<dim3((Bn * Tn + Bn + 255) / 256), 256, 0, stream>>>(captions, caption_len, out);

    // ---- recurrence: ONE fused kernel per step ----
    for (int t = 0; t < STEPSn; ++t) {
        const float* hbase = (t == 0) ? ws_h0 : (ws_hall + (size_t)(t - 1) * DECn);
        int hstride = (t == 0) ? DECn : (STEPSn * DECn);
        k_step<<<dim3(NBLK), 256, 0, stream>>>(ws_encproj, feat_bf, ws_WT, emb, captions,
                                               W_dec, b_dec, W_att, b_att, b_ih, b_hh,
                                               hbase, hstride, ws_c, ws_ctx, ws_hall,
                                               out + OUT_ALPHAS, ws_bar, t);
    }

    // ---- logits: split A, then MFMA GEMM (overwrites feat_bf stash) ----
    k_splitA<<<dim3(Bn * STEPSn * DECn / 1024), 256, 0, stream>>>(ws_hall, ws_Ah, ws_Al);
    k_logits_mfma<<<dim3(Vn / 48), 512, 0, stream>>>(ws_Ah, ws_Al, W_out, b_out, out);
}

// Round 12
// 3621.572 us; speedup vs baseline: 3.5250x; 3.5250x over previous
//
#include <hip/hip_runtime.h>
#include <hip/hip_bf16.h>
#include <cstdint>
#include <cstddef>

// Problem constants
#define Bn 64
#define Pn 196
#define ENCn 2048
#define DECn 512
#define ATTn 512
#define En 300
#define Vn 30000
#define Tn 21
#define STEPSn 20
#define Gn 2048        // 4*DEC gate width

// ---- workspace layout (float offsets) ----
#define WS_ENCPROJ ((size_t)0)                            // bf16 [64*196][512] (ushort); reused post-loop for Ah/Al
#define WS_WT    (WS_ENCPROJ + (size_t)Bn*Pn*ATTn)        // bf16 [2348][2048] (ushort) = W_ih^T
#define WS_CTX   (WS_WT + (size_t)(En+ENCn)*Gn)           // [64][2048] (also mean_f pre-loop)
#define WS_H0    (WS_CTX + (size_t)Bn*ENCn)               // [64][512]
#define WS_C     (WS_H0 + (size_t)Bn*DECn)                // [64][512]
#define WS_HALL  (WS_C + (size_t)Bn*DECn)                 // [64][20][512] row r=b*20+t
#define WS_SCORES (WS_HALL + (size_t)Bn*STEPSn*DECn)      // [64][196] raw scores

// ---- output layout (float offsets into d_out) ----
#define OUT_ALPHAS ((size_t)Bn*STEPSn*Vn)                 // 38,400,000
#define OUT_CAPT   (OUT_ALPHAS + (size_t)Bn*STEPSn*Pn)
#define OUT_SEQ    (OUT_CAPT + (size_t)Bn*Tn)
// NOTE: during the loop, d_out's logits region holds the bf16 feature copy.

typedef __attribute__((ext_vector_type(8))) short short8;
typedef __attribute__((ext_vector_type(4))) short short4v;
typedef __attribute__((ext_vector_type(4))) float f32x4;

static __device__ __forceinline__ unsigned short f2bf(float f) {
    unsigned u = __float_as_uint(f);
    return (unsigned short)((u + 0x7FFFu + ((u >> 16) & 1u)) >> 16);
}
static __device__ __forceinline__ float bf2f(unsigned short u) {
    return __uint_as_float((unsigned)u << 16);
}

// ============ enc_proj via split-bf16 MFMA; OUTPUT IS bf16 now ============
__global__ __launch_bounds__(256) void k_encproj_mfma(
        const float* __restrict__ A,
        const float* __restrict__ B,
        const float* __restrict__ bias,
        unsigned short* __restrict__ Cbf) {
    __shared__ short Ah[128][40];
    __shared__ short Al[128][40];
    __shared__ short Bh[128][40];
    __shared__ short Bl[128][40];
    int m0 = blockIdx.x * 128, n0 = blockIdx.y * 128;
    int tid = threadIdx.x;
    int w = tid >> 6, l = tid & 63;
    int lr = l & 15, lk = (l >> 4) * 8;

    f32x4 acc[2][8];
    #pragma unroll
    for (int mt = 0; mt < 2; ++mt)
        #pragma unroll
        for (int nt = 0; nt < 8; ++nt) acc[mt][nt] = (f32x4){0.f, 0.f, 0.f, 0.f};

    for (int k0 = 0; k0 < ENCn; k0 += 32) {
        __syncthreads();
        #pragma unroll
        for (int i = 0; i < 2; ++i) {
            int q = tid + i * 256;
            int r = q >> 2, c8 = (q & 3) * 8;
            const float* src = A + (size_t)(m0 + r) * ENCn + k0 + c8;
            float4 v0 = *(const float4*)src;
            float4 v1 = *(const float4*)(src + 4);
            float vv[8] = {v0.x, v0.y, v0.z, v0.w, v1.x, v1.y, v1.z, v1.w};
            short8 h8, l8;
            #pragma unroll
            for (int j = 0; j < 8; ++j) {
                unsigned short hi = f2bf(vv[j]);
                float rem = vv[j] - __uint_as_float((unsigned)hi << 16);
                h8[j] = (short)hi;
                l8[j] = (short)f2bf(rem);
            }
            *(short8*)&Ah[r][c8] = h8;
            *(short8*)&Al[r][c8] = l8;
        }
        #pragma unroll
        for (int i = 0; i < 2; ++i) {
            int q = tid + i * 256;
            int n = q & 127, kc = (q >> 7) * 8;
            float vv[8];
            #pragma unroll
            for (int j = 0; j < 8; ++j)
                vv[j] = B[(size_t)(k0 + kc + j) * ATTn + n0 + n];
            short8 h8, l8;
            #pragma unroll
            for (int j = 0; j < 8; ++j) {
                unsigned short hi = f2bf(vv[j]);
                float rem = vv[j] - __uint_as_float((unsigned)hi << 16);
                h8[j] = (short)hi;
                l8[j] = (short)f2bf(rem);
            }
            *(short8*)&Bh[n][kc] = h8;
            *(short8*)&Bl[n][kc] = l8;
        }
        __syncthreads();
        short8 ah[2], al2[2];
        #pragma unroll
        for (int mt = 0; mt < 2; ++mt) {
            int row = w * 32 + mt * 16 + lr;
            ah[mt]  = *(const short8*)&Ah[row][lk];
            al2[mt] = *(const short8*)&Al[row][lk];
        }
        #pragma unroll
        for (int nt = 0; nt < 8; ++nt) {
            short8 bh = *(const short8*)&Bh[nt * 16 + lr][lk];
            short8 bl = *(const short8*)&Bl[nt * 16 + lr][lk];
            #pragma unroll
            for (int mt = 0; mt < 2; ++mt) {
                acc[mt][nt] = __builtin_amdgcn_mfma_f32_16x16x32_bf16(ah[mt], bh, acc[mt][nt], 0, 0, 0);
                acc[mt][nt] = __builtin_amdgcn_mfma_f32_16x16x32_bf16(ah[mt], bl, acc[mt][nt], 0, 0, 0);
                acc[mt][nt] = __builtin_amdgcn_mfma_f32_16x16x32_bf16(al2[mt], bh, acc[mt][nt], 0, 0, 0);
            }
        }
    }
    #pragma unroll
    for (int mt = 0; mt < 2; ++mt) {
        #pragma unroll
        for (int nt = 0; nt < 8; ++nt) {
            int n = n0 + nt * 16 + lr;
            float bv = bias[n];
            #pragma unroll
            for (int r = 0; r < 4; ++r) {
                int m = m0 + w * 32 + mt * 16 + (l >> 4) * 4 + r;
                Cbf[(size_t)m * ATTn + n] = f2bf(acc[mt][nt][r] + bv);
            }
        }
    }
}

// ================= small precompute kernels =================

__global__ __launch_bounds__(256) void k_feat2bf(const float* __restrict__ feat,
                                                 unsigned short* __restrict__ outbf) {
    size_t idx = ((size_t)blockIdx.x * 256 + threadIdx.x) * 8;
    float4 v0 = *(const float4*)(feat + idx);
    float4 v1 = *(const float4*)(feat + idx + 4);
    float vv[8] = {v0.x, v0.y, v0.z, v0.w, v1.x, v1.y, v1.z, v1.w};
    short8 o;
    #pragma unroll
    for (int j = 0; j < 8; ++j) o[j] = (short)f2bf(vv[j]);
    *(short8*)(outbf + idx) = o;
}

__global__ __launch_bounds__(256) void k_mean(const float* __restrict__ feat,
                                              float* __restrict__ mean_f) {
    int b = blockIdx.x;
    int e = blockIdx.y * 256 + threadIdx.x;
    const float* fb = feat + (size_t)b * Pn * ENCn + e;
    float s = 0.f;
    #pragma unroll 4
    for (int p = 0; p < Pn; ++p) s += fb[(size_t)p * ENCn];
    mean_f[(size_t)b * ENCn + e] = s * (1.0f / (float)Pn);
}

__global__ __launch_bounds__(256) void k_init_state(
        const float* __restrict__ mf,
        const float* __restrict__ Wh, const float* __restrict__ bh,
        const float* __restrict__ Wc, const float* __restrict__ bc,
        float* __restrict__ h, float* __restrict__ c) {
    int n = blockIdx.x * 256 + threadIdx.x;
    int b0 = blockIdx.y * 4;
    float ah[4], ac[4];
    float bhv = bh[n], bcv = bc[n];
    #pragma unroll
    for (int j = 0; j < 4; ++j) { ah[j] = bhv; ac[j] = bcv; }
    for (int k = 0; k < ENCn; ++k) {
        float wh = Wh[(size_t)k * DECn + n];
        float wc = Wc[(size_t)k * DECn + n];
        #pragma unroll
        for (int j = 0; j < 4; ++j) {
            float a = mf[(size_t)(b0 + j) * ENCn + k];
            ah[j] += a * wh;
            ac[j] += a * wc;
        }
    }
    #pragma unroll
    for (int j = 0; j < 4; ++j) {
        h[(size_t)(b0 + j) * DECn + n] = ah[j];
        c[(size_t)(b0 + j) * DECn + n] = ac[j];
    }
}

// transpose W_ih [Gn][K] -> bf16 WT_bf [K][Gn]
__global__ __launch_bounds__(256) void k_transpose_bf(const float* __restrict__ in,
                                                      unsigned short* __restrict__ out,
                                                      int R, int C) {
    __shared__ float tile[32][33];
    int c0 = blockIdx.x * 32, r0 = blockIdx.y * 32;
    int tx = threadIdx.x & 31, ty = threadIdx.x >> 5;
    for (int i = ty; i < 32; i += 8) {
        int r = r0 + i, cc = c0 + tx;
        tile[i][tx] = (r < R && cc < C) ? in[(size_t)r * C + cc] : 0.f;
    }
    __syncthreads();
    for (int i = ty; i < 32; i += 8) {
        int cc = c0 + i, r = r0 + tx;
        if (cc < C && r < R) out[(size_t)cc * R + r] = f2bf(tile[tx][i]);
    }
}

__global__ __launch_bounds__(256) void k_tail(const int* __restrict__ captions,
                                              const int* __restrict__ caption_len,
                                              float* __restrict__ out) {
    int i = blockIdx.x * 256 + threadIdx.x;
    if (i < Bn * Tn) {
        out[OUT_CAPT + i] = (float)captions[i];
    } else if (i < Bn * Tn + Bn) {
        int b = i - Bn * Tn;
        out[OUT_SEQ + b] = (float)(caption_len[b] - 1);
    }
}

// ================= per-step kernel A: hdec + raw scores =================
// 256 blocks: b = bid>>2, q = bid&3 -> p-range [q*49, q*49+49). hdec computed
// redundantly per quarter (verbatim R10 text); per-p score text verbatim
// (wave-owned, lane-strided) but enc_proj is now bf16.
__global__ __launch_bounds__(256) void k_scores(const unsigned short* __restrict__ enc_proj,
                                                const float* __restrict__ hbase, int hstride,
                                                const float* __restrict__ W_dec,
                                                const float* __restrict__ b_dec,
                                                const float* __restrict__ W_att,
                                                const float* __restrict__ b_att,
                                                float* __restrict__ scores) {
    __shared__ float hv[DECn];
    __shared__ float hs[ATTn];
    __shared__ float wa[ATTn];
    int bid = blockIdx.x;
    int b = bid >> 2, q = bid & 3;
    int tid = threadIdx.x;
    hv[tid]       = hbase[(size_t)b * hstride + tid];
    hv[tid + 256] = hbase[(size_t)b * hstride + tid + 256];
    wa[tid]       = W_att[tid];
    wa[tid + 256] = W_att[tid + 256];
    __syncthreads();
    {
        float acc0 = b_dec[tid], acc1 = b_dec[tid + 256];
        const float* wd = W_dec + tid;
        #pragma unroll 8
        for (int k = 0; k < DECn; ++k) {
            float h = hv[k];
            acc0 += h * wd[(size_t)k * DECn];
            acc1 += h * wd[(size_t)k * DECn + 256];
        }
        hs[tid] = acc0;
        hs[tid + 256] = acc1;
    }
    __syncthreads();
    int wv = tid >> 6, lane = tid & 63;
    float batt = b_att[0];
    for (int p = q * 49 + wv; p < q * 49 + 49; p += 4) {
        const unsigned short* ep = enc_proj + ((size_t)b * Pn + p) * ATTn;
        float s = 0.f;
        #pragma unroll 2
        for (int a = lane; a < ATTn; a += 64) {
            float v = bf2f(ep[a]) + hs[a];
            s += fmaxf(v, 0.f) * wa[a];
        }
        #pragma unroll
        for (int off = 32; off > 0; off >>= 1) s += __shfl_xor(s, off);
        if (lane == 0) scores[(size_t)b * Pn + p] = s + batt;
    }
}

// ================= per-step kernel B: softmax + ctx =================
// 512 blocks: b = bid>>3, y = bid&7. Softmax redundant per y (R10 reduction
// order); y==0 writes alphas. ctx body verbatim R10 k_ctx_bf.
__global__ __launch_bounds__(256) void k_ctxsm(const unsigned short* __restrict__ fbf,
                                               const float* __restrict__ scores,
                                               float* __restrict__ alphas_out,
                                               float* __restrict__ ctx, int t) {
    __shared__ float al[Pn];
    __shared__ float red[4];
    __shared__ unsigned short Fl[32][256];
    int bid = blockIdx.x;
    int b = bid >> 3, y = bid & 7;
    int tid = threadIdx.x;
    int wv = tid >> 6, lane = tid & 63;
    float v = (tid < Pn) ? scores[(size_t)b * Pn + tid] : -1e30f;
    float m = v;
    #pragma unroll
    for (int off = 32; off > 0; off >>= 1) m = fmaxf(m, __shfl_xor(m, off));
    if (lane == 0) red[wv] = m;
    __syncthreads();
    float M = fmaxf(fmaxf(red[0], red[1]), fmaxf(red[2], red[3]));
    __syncthreads();
    float e = (tid < Pn) ? expf(v - M) : 0.f;
    float s = e;
    #pragma unroll
    for (int off = 32; off > 0; off >>= 1) s += __shfl_xor(s, off);
    if (lane == 0) red[wv] = s;
    __syncthreads();
    float S = red[0] + red[1] + red[2] + red[3];
    float an = e / S;
    if (tid < Pn) {
        al[tid] = an;
        if (y == 0) alphas_out[((size_t)b * STEPSn + t) * Pn + tid] = an;
    }
    const unsigned short* fb = fbf + (size_t)b * Pn * ENCn + (size_t)y * 256;
    float acc0 = 0.f;
    int p0 = 0;
    for (int pc = 0; pc < 7; ++pc) {
        int rows = (pc < 6) ? 32 : 4;   // 196 = 6*32 + 4
        __syncthreads();
        for (int q = tid; q < rows * 32; q += 256) {
            int pr = q >> 5, c8 = (q & 31) * 8;
            *(short8*)&Fl[pr][c8] =
                *(const short8*)&fb[(size_t)(p0 + pr) * ENCn + c8];
        }
        __syncthreads();
        #pragma unroll 4
        for (int pr = 0; pr < rows; ++pr) {
            float fv = bf2f(Fl[pr][tid]);
            acc0 += al[p0 + pr] * fv;
        }
        p0 += rows;
    }
    ctx[(size_t)b * ENCn + y * 256 + tid] = acc0;
}

// ================= per-step kernel C: gates + LSTM (bf16 weights) =================
// 512 blocks: x = bid&31, ybk = bid>>5. MAC text identical to R10; Wl staged
// from bf16 WT (converted to fp32 in LDS).
__global__ __launch_bounds__(256) void k_gates(const unsigned short* __restrict__ WT,
                                               const float* __restrict__ emb,
                                               const int* __restrict__ captions,
                                               const float* __restrict__ ctx,
                                               const float* __restrict__ hbase, int hstride,
                                               const float* __restrict__ b_ih,
                                               const float* __restrict__ b_hh,
                                               float* __restrict__ c,
                                               float* __restrict__ hall, int t) {
    __shared__ float Ap[4][516];
    __shared__ float Wl[64][64];
    __shared__ float sg[4][16][4];
    int bid = blockIdx.x;
    int x = bid & 31, ybk = bid >> 5;
    int tid = threadIdx.x;
    int lane = tid & 63, wv = tid >> 6;
    int gate = lane >> 4, dd = lane & 15;
    int g = (gate << 9) + x * 16 + dd;
    int b0 = ybk * 4;

    float bias = b_ih[g] + b_hh[g];
    float acc0 = bias;

    const int cbase[6] = {0, 512, 1024, 1536, 2048, 2560};
    for (int ch = 0; ch < 6; ++ch) {
        int base = cbase[ch];
        int klen = (ch == 5) ? 300 : 512;
        __syncthreads();
        int qpb = klen >> 2;
        for (int q = tid; q < (qpb << 2); q += 256) {
            int bb = q / qpb;
            int kq = q - bb * qpb;
            int kg = base + kq * 4;
            int bglob = b0 + bb;
            const float* src;
            if (kg < En) src = emb + (size_t)captions[bglob * Tn + t] * En + kg;
            else if (kg < En + ENCn) src = ctx + (size_t)bglob * ENCn + (kg - En);
            else src = hbase + (size_t)bglob * hstride + (kg - En - ENCn);
            *(float4*)&Ap[bb][kq * 4] = *(const float4*)src;
        }
        for (int sub = 0; sub < klen; sub += 64) {
            int rows = (klen - sub < 64) ? (klen - sub) : 64;
            __syncthreads();
            // stage Wl[rows][64] from bf16: tasks = rows*8, each = 8 cols
            for (int q = tid; q < rows * 8; q += 256) {
                int kr = q >> 3, c8 = (q & 7) * 8;
                int seg = c8 >> 4, rem = c8 & 15;
                int gg = (seg << 9) + x * 16 + rem;
                short8 wv8 = *(const short8*)&WT[(size_t)(base + sub + kr) * Gn + gg];
                #pragma unroll
                for (int j = 0; j < 8; ++j)
                    Wl[kr][c8 + j] = bf2f((unsigned short)wv8[j]);
            }
            __syncthreads();
            const float* a0p = &Ap[wv][sub];
            #pragma unroll 4
            for (int k = 0; k < rows; ++k) {
                acc0 += Wl[k][lane] * a0p[k];
            }
        }
    }
    sg[gate][dd][wv] = acc0;
    __syncthreads();
    if (tid < 64) {
        int dl = tid & 15, bl = tid >> 4;
        float gi = sg[0][dl][bl], gf = sg[1][dl][bl];
        float gg = sg[2][dl][bl], go = sg[3][dl][bl];
        int bglob = b0 + bl, d = x * 16 + dl;
        float si = 1.f / (1.f + expf(-gi));
        float sf = 1.f / (1.f + expf(-gf));
        float so = 1.f / (1.f + expf(-go));
        size_t cidx = (size_t)bglob * DECn + d;
        float cc = sf * c[cidx] + si * tanhf(gg);
        float hh = so * tanhf(cc);
        c[cidx] = cc;
        hall[((size_t)bglob * STEPSn + t) * DECn + d] = hh;
    }
}

// ================= logits via split-bf16 MFMA =================

__global__ __launch_bounds__(256) void k_splitA(const float* __restrict__ hall,
                                                short* __restrict__ Ah,
                                                short* __restrict__ Al) {
    int idx = blockIdx.x * 256 + threadIdx.x;
    size_t base = (size_t)idx * 4;
    float4 v = *(const float4*)(hall + base);
    float a[4] = {v.x, v.y, v.z, v.w};
    short4v h, l;
    #pragma unroll
    for (int j = 0; j < 4; ++j) {
        unsigned short hi = f2bf(a[j]);
        float lo = a[j] - __uint_as_float((unsigned)hi << 16);
        h[j] = (short)hi;
        l[j] = (short)f2bf(lo);
    }
    *(short4v*)(Ah + base) = h;
    *(short4v*)(Al + base) = l;
}

__global__ __launch_bounds__(512) void k_logits_mfma(const short* __restrict__ Ah,
                                                     const short* __restrict__ Al,
                                                     const float* __restrict__ W_out,
                                                     const float* __restrict__ b_out,
                                                     float* __restrict__ out) {
    __shared__ short Bh[48][520];
    __shared__ short Bl[48][520];
    int n0 = blockIdx.x * 48;
    int tid = threadIdx.x;
    for (int q = tid; q < 6144; q += 512) {
        int cq = q % 12, k = q / 12;
        const float* src = W_out + (size_t)k * Vn + n0 + cq * 4;
        float4 v = *(const float4*)src;
        float a[4] = {v.x, v.y, v.z, v.w};
        #pragma unroll
        for (int j = 0; j < 4; ++j) {
            unsigned short hi = f2bf(a[j]);
            float lo = a[j] - __uint_as_float((unsigned)hi << 16);
            Bh[cq * 4 + j][k] = (short)hi;
            Bl[cq * 4 + j][k] = (short)f2bf(lo);
        }
    }
    __syncthreads();
    int w = tid >> 6, l = tid & 63;
    int lr = l & 15, lk = (l >> 4) * 8;
    float bias[3];
    #pragma unroll
    for (int nt = 0; nt < 3; ++nt) bias[nt] = b_out[n0 + nt * 16 + lr];

    for (int chunk = 0; chunk < 10; ++chunk) {
        int m0 = chunk * 128 + w * 16;
        f32x4 acc[3];
        #pragma unroll
        for (int nt = 0; nt < 3; ++nt) acc[nt] = (f32x4){0.f, 0.f, 0.f, 0.f};
        #pragma unroll 2
        for (int ks = 0; ks < 16; ++ks) {
            int k0 = ks * 32;
            short8 ah = *(const short8*)(Ah + (size_t)(m0 + lr) * DECn + k0 + lk);
            short8 al = *(const short8*)(Al + (size_t)(m0 + lr) * DECn + k0 + lk);
            #pragma unroll
            for (int nt = 0; nt < 3; ++nt) {
                short8 bh = *(const short8*)&Bh[nt * 16 + lr][k0 + lk];
                short8 bl = *(const short8*)&Bl[nt * 16 + lr][k0 + lk];
                acc[nt] = __builtin_amdgcn_mfma_f32_16x16x32_bf16(ah, bh, acc[nt], 0, 0, 0);
                acc[nt] = __builtin_amdgcn_mfma_f32_16x16x32_bf16(ah, bl, acc[nt], 0, 0, 0);
                acc[nt] = __builtin_amdgcn_mfma_f32_16x16x32_bf16(al, bh, acc[nt], 0, 0, 0);
            }
        }
        #pragma unroll
        for (int nt = 0; nt < 3; ++nt) {
            int n = n0 + nt * 16 + lr;
            #pragma unroll
            for (int r = 0; r < 4; ++r) {
                int m = m0 + (l >> 4) * 4 + r;
                out[(size_t)m * Vn + n] = acc[nt][r] + bias[nt];
            }
        }
    }
}

// ================= launcher =================

extern "C" void kernel_launch(void* const* d_in, const int* in_sizes, int n_in,
                              void* d_out, int out_size, void* d_ws, size_t ws_size,
                              hipStream_t stream) {
    const float* features    = (const float*)d_in[0];
    const int*   captions    = (const int*)d_in[1];
    const int*   caption_len = (const int*)d_in[2];
    const float* emb         = (const float*)d_in[3];
    const float* W_enc       = (const float*)d_in[4];
    const float* b_enc       = (const float*)d_in[5];
    const float* W_dec       = (const float*)d_in[6];
    const float* b_dec       = (const float*)d_in[7];
    const float* W_att       = (const float*)d_in[8];
    const float* b_att       = (const float*)d_in[9];
    const float* W_h0        = (const float*)d_in[10];
    const float* b_h0        = (const float*)d_in[11];
    const float* W_c0        = (const float*)d_in[12];
    const float* b_c0        = (const float*)d_in[13];
    const float* W_ih        = (const float*)d_in[14];
    const float* b_ih        = (const float*)d_in[15];
    const float* W_hh        = (const float*)d_in[16];
    const float* b_hh        = (const float*)d_in[17];
    const float* W_out       = (const float*)d_in[18];
    const float* b_out       = (const float*)d_in[19];

    float* out = (float*)d_out;
    float* ws  = (float*)d_ws;

    unsigned short* ws_encproj = (unsigned short*)(ws + WS_ENCPROJ);
    unsigned short* ws_WT      = (unsigned short*)(ws + WS_WT);
    float* ws_ctx     = ws + WS_CTX;
    float* ws_h0      = ws + WS_H0;
    float* ws_c       = ws + WS_C;
    float* ws_hall    = ws + WS_HALL;
    float* ws_scores  = ws + WS_SCORES;
    short* ws_Ah      = (short*)(ws + WS_ENCPROJ);       // reuse enc_proj region post-loop
    short* ws_Al      = ws_Ah + (size_t)Bn * STEPSn * DECn;
    unsigned short* feat_bf = (unsigned short*)out;      // stash in unused logits region

    // ---- precompute ----
    k_feat2bf<<<dim3(Bn * Pn * ENCn / 2048), 256, 0, stream>>>(features, feat_bf);
    k_encproj_mfma<<<dim3(Pn * Bn / 128, ATTn / 128), 256, 0, stream>>>(
        features, W_enc, b_enc, ws_encproj);
    k_mean<<<dim3(Bn, ENCn / 256), 256, 0, stream>>>(features, ws_ctx);
    k_transpose_bf<<<dim3((En + ENCn + 31) / 32, Gn / 32), 256, 0, stream>>>(
        W_ih, ws_WT, Gn, En + ENCn);
    k_init_state<<<dim3(2, 16), 256, 0, stream>>>(ws_ctx, W_h0, b_h0, W_c0, b_c0,
                                                  ws_h0, ws_c);
    k_tail<<<dim3((Bn * Tn + Bn + 255) / 256), 256, 0, stream>>>(captions, caption_len, out);

    // ---- recurrence: 3 kernels per step ----
    for (int t = 0; t < STEPSn; ++t) {
        const float* hbase = (t == 0) ? ws_h0 : (ws_hall + (size_t)(t - 1) * DECn);
        int hstride = (t == 0) ? DECn : (STEPSn * DECn);
        k_scores<<<dim3(256), 256, 0, stream>>>(ws_encproj, hbase, hstride,
                                                W_dec, b_dec, W_att, b_att, ws_scores);
        k_ctxsm<<<dim3(512), 256, 0, stream>>>(feat_bf, ws_scores,
                                               out + OUT_ALPHAS, ws_ctx, t);
        k_gates<<<dim3(512), 256, 0, stream>>>(ws_WT, emb, captions, ws_ctx,
                                               hbase, hstride, b_ih, b_hh,
                                               ws_c, ws_hall, t);
    }

    // ---- logits: split A, then MFMA GEMM (overwrites feat_bf stash) ----
    k_splitA<<<dim3(Bn * STEPSn * DECn / 1024), 256, 0, stream>>>(ws_hall, ws_Ah, ws_Al);
    k_logits_mfma<<<dim3(Vn / 48), 512, 0, stream>>>(ws_Ah, ws_Al, W_out, b_out, out);
}

// Round 13
// 3019.055 us; speedup vs baseline: 4.2285x; 1.1996x over previous
//
#include <hip/hip_runtime.h>
#include <hip/hip_bf16.h>
#include <cstdint>
#include <cstddef>

// Problem constants
#define Bn 64
#define Pn 196
#define ENCn 2048
#define DECn 512
#define ATTn 512
#define En 300
#define Vn 30000
#define Tn 21
#define STEPSn 20
#define Gn 2048        // 4*DEC gate width
#define KALLn 2860     // En + ENCn + DECn

// ---- workspace layout (float offsets) ----
#define WS_ENCPROJ ((size_t)0)                            // bf16 [64*196][512] (ushort); reused post-loop for Ah/Al
#define WS_WT    (WS_ENCPROJ + (size_t)Bn*Pn*ATTn)        // bf16 [2348][2048] (ushort) = W_ih^T
#define WS_CTX   (WS_WT + (size_t)(En+ENCn)*Gn)           // [64][2048] (also mean_f pre-loop)
#define WS_H0    (WS_CTX + (size_t)Bn*ENCn)               // [64][512]
#define WS_C     (WS_H0 + (size_t)Bn*DECn)                // [64][512]
#define WS_HALL  (WS_C + (size_t)Bn*DECn)                 // [64][20][512] row r=b*20+t
#define WS_SCORES (WS_HALL + (size_t)Bn*STEPSn*DECn)      // [64][196] raw scores

// ---- output layout (float offsets into d_out) ----
#define OUT_ALPHAS ((size_t)Bn*STEPSn*Vn)                 // 38,400,000
#define OUT_CAPT   (OUT_ALPHAS + (size_t)Bn*STEPSn*Pn)
#define OUT_SEQ    (OUT_CAPT + (size_t)Bn*Tn)
// NOTE: during the loop, d_out's logits region holds the bf16 feature copy.

typedef __attribute__((ext_vector_type(8))) short short8;
typedef __attribute__((ext_vector_type(4))) short short4v;
typedef __attribute__((ext_vector_type(4))) float f32x4;

static __device__ __forceinline__ unsigned short f2bf(float f) {
    unsigned u = __float_as_uint(f);
    return (unsigned short)((u + 0x7FFFu + ((u >> 16) & 1u)) >> 16);
}
static __device__ __forceinline__ float bf2f(unsigned short u) {
    return __uint_as_float((unsigned)u << 16);
}

// ============ enc_proj via split-bf16 MFMA; bf16 output (verbatim R12) ============
__global__ __launch_bounds__(256) void k_encproj_mfma(
        const float* __restrict__ A,
        const float* __restrict__ B,
        const float* __restrict__ bias,
        unsigned short* __restrict__ Cbf) {
    __shared__ short Ah[128][40];
    __shared__ short Al[128][40];
    __shared__ short Bh[128][40];
    __shared__ short Bl[128][40];
    int m0 = blockIdx.x * 128, n0 = blockIdx.y * 128;
    int tid = threadIdx.x;
    int w = tid >> 6, l = tid & 63;
    int lr = l & 15, lk = (l >> 4) * 8;

    f32x4 acc[2][8];
    #pragma unroll
    for (int mt = 0; mt < 2; ++mt)
        #pragma unroll
        for (int nt = 0; nt < 8; ++nt) acc[mt][nt] = (f32x4){0.f, 0.f, 0.f, 0.f};

    for (int k0 = 0; k0 < ENCn; k0 += 32) {
        __syncthreads();
        #pragma unroll
        for (int i = 0; i < 2; ++i) {
            int q = tid + i * 256;
            int r = q >> 2, c8 = (q & 3) * 8;
            const float* src = A + (size_t)(m0 + r) * ENCn + k0 + c8;
            float4 v0 = *(const float4*)src;
            float4 v1 = *(const float4*)(src + 4);
            float vv[8] = {v0.x, v0.y, v0.z, v0.w, v1.x, v1.y, v1.z, v1.w};
            short8 h8, l8;
            #pragma unroll
            for (int j = 0; j < 8; ++j) {
                unsigned short hi = f2bf(vv[j]);
                float rem = vv[j] - __uint_as_float((unsigned)hi << 16);
                h8[j] = (short)hi;
                l8[j] = (short)f2bf(rem);
            }
            *(short8*)&Ah[r][c8] = h8;
            *(short8*)&Al[r][c8] = l8;
        }
        #pragma unroll
        for (int i = 0; i < 2; ++i) {
            int q = tid + i * 256;
            int n = q & 127, kc = (q >> 7) * 8;
            float vv[8];
            #pragma unroll
            for (int j = 0; j < 8; ++j)
                vv[j] = B[(size_t)(k0 + kc + j) * ATTn + n0 + n];
            short8 h8, l8;
            #pragma unroll
            for (int j = 0; j < 8; ++j) {
                unsigned short hi = f2bf(vv[j]);
                float rem = vv[j] - __uint_as_float((unsigned)hi << 16);
                h8[j] = (short)hi;
                l8[j] = (short)f2bf(rem);
            }
            *(short8*)&Bh[n][kc] = h8;
            *(short8*)&Bl[n][kc] = l8;
        }
        __syncthreads();
        short8 ah[2], al2[2];
        #pragma unroll
        for (int mt = 0; mt < 2; ++mt) {
            int row = w * 32 + mt * 16 + lr;
            ah[mt]  = *(const short8*)&Ah[row][lk];
            al2[mt] = *(const short8*)&Al[row][lk];
        }
        #pragma unroll
        for (int nt = 0; nt < 8; ++nt) {
            short8 bh = *(const short8*)&Bh[nt * 16 + lr][lk];
            short8 bl = *(const short8*)&Bl[nt * 16 + lr][lk];
            #pragma unroll
            for (int mt = 0; mt < 2; ++mt) {
                acc[mt][nt] = __builtin_amdgcn_mfma_f32_16x16x32_bf16(ah[mt], bh, acc[mt][nt], 0, 0, 0);
                acc[mt][nt] = __builtin_amdgcn_mfma_f32_16x16x32_bf16(ah[mt], bl, acc[mt][nt], 0, 0, 0);
                acc[mt][nt] = __builtin_amdgcn_mfma_f32_16x16x32_bf16(al2[mt], bh, acc[mt][nt], 0, 0, 0);
            }
        }
    }
    #pragma unroll
    for (int mt = 0; mt < 2; ++mt) {
        #pragma unroll
        for (int nt = 0; nt < 8; ++nt) {
            int n = n0 + nt * 16 + lr;
            float bv = bias[n];
            #pragma unroll
            for (int r = 0; r < 4; ++r) {
                int m = m0 + w * 32 + mt * 16 + (l >> 4) * 4 + r;
                Cbf[(size_t)m * ATTn + n] = f2bf(acc[mt][nt][r] + bv);
            }
        }
    }
}

// ================= small precompute kernels =================

__global__ __launch_bounds__(256) void k_feat2bf(const float* __restrict__ feat,
                                                 unsigned short* __restrict__ outbf) {
    size_t idx = ((size_t)blockIdx.x * 256 + threadIdx.x) * 8;
    float4 v0 = *(const float4*)(feat + idx);
    float4 v1 = *(const float4*)(feat + idx + 4);
    float vv[8] = {v0.x, v0.y, v0.z, v0.w, v1.x, v1.y, v1.z, v1.w};
    short8 o;
    #pragma unroll
    for (int j = 0; j < 8; ++j) o[j] = (short)f2bf(vv[j]);
    *(short8*)(outbf + idx) = o;
}

__global__ __launch_bounds__(256) void k_mean(const float* __restrict__ feat,
                                              float* __restrict__ mean_f) {
    int b = blockIdx.x;
    int e = blockIdx.y * 256 + threadIdx.x;
    const float* fb = feat + (size_t)b * Pn * ENCn + e;
    float s = 0.f;
    #pragma unroll 4
    for (int p = 0; p < Pn; ++p) s += fb[(size_t)p * ENCn];
    mean_f[(size_t)b * ENCn + e] = s * (1.0f / (float)Pn);
}

__global__ __launch_bounds__(256) void k_init_state(
        const float* __restrict__ mf,
        const float* __restrict__ Wh, const float* __restrict__ bh,
        const float* __restrict__ Wc, const float* __restrict__ bc,
        float* __restrict__ h, float* __restrict__ c) {
    int n = blockIdx.x * 256 + threadIdx.x;
    int b0 = blockIdx.y * 4;
    float ah[4], ac[4];
    float bhv = bh[n], bcv = bc[n];
    #pragma unroll
    for (int j = 0; j < 4; ++j) { ah[j] = bhv; ac[j] = bcv; }
    for (int k = 0; k < ENCn; ++k) {
        float wh = Wh[(size_t)k * DECn + n];
        float wc = Wc[(size_t)k * DECn + n];
        #pragma unroll
        for (int j = 0; j < 4; ++j) {
            float a = mf[(size_t)(b0 + j) * ENCn + k];
            ah[j] += a * wh;
            ac[j] += a * wc;
        }
    }
    #pragma unroll
    for (int j = 0; j < 4; ++j) {
        h[(size_t)(b0 + j) * DECn + n] = ah[j];
        c[(size_t)(b0 + j) * DECn + n] = ac[j];
    }
}

// transpose W_ih [Gn][K] -> bf16 WT_bf [K][Gn]
__global__ __launch_bounds__(256) void k_transpose_bf(const float* __restrict__ in,
                                                      unsigned short* __restrict__ out,
                                                      int R, int C) {
    __shared__ float tile[32][33];
    int c0 = blockIdx.x * 32, r0 = blockIdx.y * 32;
    int tx = threadIdx.x & 31, ty = threadIdx.x >> 5;
    for (int i = ty; i < 32; i += 8) {
        int r = r0 + i, cc = c0 + tx;
        tile[i][tx] = (r < R && cc < C) ? in[(size_t)r * C + cc] : 0.f;
    }
    __syncthreads();
    for (int i = ty; i < 32; i += 8) {
        int cc = c0 + i, r = r0 + tx;
        if (cc < C && r < R) out[(size_t)cc * R + r] = f2bf(tile[tx][i]);
    }
}

__global__ __launch_bounds__(256) void k_tail(const int* __restrict__ captions,
                                              const int* __restrict__ caption_len,
                                              float* __restrict__ out) {
    int i = blockIdx.x * 256 + threadIdx.x;
    if (i < Bn * Tn) {
        out[OUT_CAPT + i] = (float)captions[i];
    } else if (i < Bn * Tn + Bn) {
        int b = i - Bn * Tn;
        out[OUT_SEQ + b] = (float)(caption_len[b] - 1);
    }
}

// ================= per-step kernel A: hdec + raw scores =================
// 256 blocks: b = bid>>2, q = bid&3. Score a-loop fully unrolled (8 independent
// loads); partial-sum order unchanged vs R12.
__global__ __launch_bounds__(256) void k_scores(const unsigned short* __restrict__ enc_proj,
                                                const float* __restrict__ hbase, int hstride,
                                                const float* __restrict__ W_dec,
                                                const float* __restrict__ b_dec,
                                                const float* __restrict__ W_att,
                                                const float* __restrict__ b_att,
                                                float* __restrict__ scores) {
    __shared__ float hv[DECn];
    __shared__ float hs[ATTn];
    __shared__ float wa[ATTn];
    int bid = blockIdx.x;
    int b = bid >> 2, q = bid & 2 ? (bid & 3) : (bid & 3);  // = bid & 3
    q = bid & 3;
    int tid = threadIdx.x;
    hv[tid]       = hbase[(size_t)b * hstride + tid];
    hv[tid + 256] = hbase[(size_t)b * hstride + tid + 256];
    wa[tid]       = W_att[tid];
    wa[tid + 256] = W_att[tid + 256];
    __syncthreads();
    {
        float acc0 = b_dec[tid], acc1 = b_dec[tid + 256];
        const float* wd = W_dec + tid;
        #pragma unroll 8
        for (int k = 0; k < DECn; ++k) {
            float h = hv[k];
            acc0 += h * wd[(size_t)k * DECn];
            acc1 += h * wd[(size_t)k * DECn + 256];
        }
        hs[tid] = acc0;
        hs[tid + 256] = acc1;
    }
    __syncthreads();
    int wv = tid >> 6, lane = tid & 63;
    float batt = b_att[0];
    for (int p = q * 49 + wv; p < q * 49 + 49; p += 4) {
        const unsigned short* ep = enc_proj + ((size_t)b * Pn + p) * ATTn;
        float s = 0.f;
        #pragma unroll
        for (int a = lane; a < ATTn; a += 64) {
            float v = bf2f(ep[a]) + hs[a];
            s += fmaxf(v, 0.f) * wa[a];
        }
        #pragma unroll
        for (int off = 32; off > 0; off >>= 1) s += __shfl_xor(s, off);
        if (lane == 0) scores[(size_t)b * Pn + p] = s + batt;
    }
}

// ================= per-step kernel B: softmax + ctx (direct-stream) =================
// 512 blocks: b = bid>>3, y = bid&7. Softmax redundant per y (R12 reduction
// order). ctx: per-thread column stream, 16 independent loads per iter,
// p ascending single acc -> bit-identical values/order vs R12.
__global__ __launch_bounds__(256) void k_ctxsm(const unsigned short* __restrict__ fbf,
                                               const float* __restrict__ scores,
                                               float* __restrict__ alphas_out,
                                               float* __restrict__ ctx, int t) {
    __shared__ float al[Pn];
    __shared__ float red[4];
    int bid = blockIdx.x;
    int b = bid >> 3, y = bid & 7;
    int tid = threadIdx.x;
    int wv = tid >> 6, lane = tid & 63;
    float v = (tid < Pn) ? scores[(size_t)b * Pn + tid] : -1e30f;
    float m = v;
    #pragma unroll
    for (int off = 32; off > 0; off >>= 1) m = fmaxf(m, __shfl_xor(m, off));
    if (lane == 0) red[wv] = m;
    __syncthreads();
    float M = fmaxf(fmaxf(red[0], red[1]), fmaxf(red[2], red[3]));
    __syncthreads();
    float e = (tid < Pn) ? expf(v - M) : 0.f;
    float s = e;
    #pragma unroll
    for (int off = 32; off > 0; off >>= 1) s += __shfl_xor(s, off);
    if (lane == 0) red[wv] = s;
    __syncthreads();
    float S = red[0] + red[1] + red[2] + red[3];
    float an = e / S;
    if (tid < Pn) {
        al[tid] = an;
        if (y == 0) alphas_out[((size_t)b * STEPSn + t) * Pn + tid] = an;
    }
    __syncthreads();
    const unsigned short* fb = fbf + (size_t)b * Pn * ENCn + (size_t)y * 256 + tid;
    float acc0 = 0.f;
    int p = 0;
    for (int pc = 0; pc < 12; ++pc) {
        float fv[16];
        #pragma unroll
        for (int j = 0; j < 16; ++j) fv[j] = bf2f(fb[(size_t)(p + j) * ENCn]);
        #pragma unroll
        for (int j = 0; j < 16; ++j) acc0 += al[p + j] * fv[j];
        p += 16;
    }
    {
        float fv[4];
        #pragma unroll
        for (int j = 0; j < 4; ++j) fv[j] = bf2f(fb[(size_t)(p + j) * ENCn]);
        #pragma unroll
        for (int j = 0; j < 4; ++j) acc0 += al[p + j] * fv[j];
    }
    ctx[(size_t)b * ENCn + y * 256 + tid] = acc0;
}

// ================= per-step kernel C: gates + LSTM (dbuf weights) =================
// 512 blocks: x = bid&31, ybk = bid>>5. Full A-panel staged upfront; flat 45
// chunks of 64 k-rows (same boundaries as R12: 512-multiples are 64-multiples)
// with double-buffered Wl + register-staged prefetch. MAC values/order
// identical to R12 -> bit-exact.
__global__ __launch_bounds__(256) void k_gates(const unsigned short* __restrict__ WT,
                                               const float* __restrict__ emb,
                                               const int* __restrict__ captions,
                                               const float* __restrict__ ctx,
                                               const float* __restrict__ hbase, int hstride,
                                               const float* __restrict__ b_ih,
                                               const float* __restrict__ b_hh,
                                               float* __restrict__ c,
                                               float* __restrict__ hall, int t) {
    __shared__ float Ap[4][KALLn];      // 45,760 B
    __shared__ float Wl[2][64][64];     // 32,768 B
    __shared__ float sg[4][16][4];
    int bid = blockIdx.x;
    int x = bid & 31, ybk = bid >> 5;
    int tid = threadIdx.x;
    int lane = tid & 63, wv = tid >> 6;
    int gate = lane >> 4, dd = lane & 15;
    int g = (gate << 9) + x * 16 + dd;
    int b0 = ybk * 4;

    float bias = b_ih[g] + b_hh[g];
    float acc0 = bias;

    // ---- stage full A-panel [4][2860] (float4 tasks; 11-12 per thread) ----
    for (int q = tid; q < 715 * 4; q += 256) {
        int bb = q / 715;
        int kq = q - bb * 715;
        int kg = kq * 4;
        int bglob = b0 + bb;
        const float* src;
        if (kg < En) src = emb + (size_t)captions[bglob * Tn + t] * En + kg;
        else if (kg < En + ENCn) src = ctx + (size_t)bglob * ENCn + (kg - En);
        else src = hbase + (size_t)bglob * hstride + (kg - En - ENCn);
        *(float4*)&Ap[bb][kg] = *(const float4*)src;
    }
    // ---- stage Wl chunk 0 ----
    {
        int rows = 64;
        for (int q = tid; q < rows * 8; q += 256) {
            int kr = q >> 3, c8 = (q & 7) * 8;
            int seg = c8 >> 4, rem = c8 & 15;
            int gg = (seg << 9) + x * 16 + rem;
            short8 wv8 = *(const short8*)&WT[(size_t)kr * Gn + gg];
            #pragma unroll
            for (int j = 0; j < 8; ++j)
                Wl[0][kr][c8 + j] = bf2f((unsigned short)wv8[j]);
        }
    }
    __syncthreads();

    int buf = 0;
    for (int cidx = 0; cidx < 45; ++cidx) {
        int k0 = cidx * 64;
        int rows = (cidx < 44) ? 64 : 44;   // 2860 = 44*64 + 44
        // prefetch next chunk into regs (issued before MAC; latency hidden)
        short8 pre0, pre1;
        bool have_next = (cidx + 1 < 45);
        int nrows = ((cidx + 1) < 44) ? 64 : 44;
        int q0 = tid, q1 = tid + 256;
        bool v0 = false, v1 = false;
        if (have_next) {
            int nk0 = k0 + 64;
            v0 = q0 < nrows * 8;
            v1 = q1 < nrows * 8;
            if (v0) {
                int kr = q0 >> 3, c8 = (q0 & 7) * 8;
                int seg = c8 >> 4, rem = c8 & 15;
                int gg = (seg << 9) + x * 16 + rem;
                pre0 = *(const short8*)&WT[(size_t)(nk0 + kr) * Gn + gg];
            }
            if (v1) {
                int kr = q1 >> 3, c8 = (q1 & 7) * 8;
                int seg = c8 >> 4, rem = c8 & 15;
                int gg = (seg << 9) + x * 16 + rem;
                pre1 = *(const short8*)&WT[(size_t)(nk0 + kr) * Gn + gg];
            }
        }
        // MAC from current buffer
        const float* a0p = &Ap[wv][k0];
        const float (*wl)[64] = Wl[buf];
        #pragma unroll 4
        for (int k = 0; k < rows; ++k) {
            acc0 += wl[k][lane] * a0p[k];
        }
        if (have_next) {
            __syncthreads();   // everyone done reading buf^1 from two chunks ago
            if (v0) {
                int kr = q0 >> 3, c8 = (q0 & 7) * 8;
                #pragma unroll
                for (int j = 0; j < 8; ++j)
                    Wl[buf ^ 1][kr][c8 + j] = bf2f((unsigned short)pre0[j]);
            }
            if (v1) {
                int kr = q1 >> 3, c8 = (q1 & 7) * 8;
                #pragma unroll
                for (int j = 0; j < 8; ++j)
                    Wl[buf ^ 1][kr][c8 + j] = bf2f((unsigned short)pre1[j]);
            }
            __syncthreads();
            buf ^= 1;
        }
    }
    sg[gate][dd][wv] = acc0;
    __syncthreads();
    if (tid < 64) {
        int dl = tid & 15, bl = tid >> 4;
        float gi = sg[0][dl][bl], gf = sg[1][dl][bl];
        float gg = sg[2][dl][bl], go = sg[3][dl][bl];
        int bglob = b0 + bl, d = x * 16 + dl;
        float si = 1.f / (1.f + expf(-gi));
        float sf = 1.f / (1.f + expf(-gf));
        float so = 1.f / (1.f + expf(-go));
        size_t cidx2 = (size_t)bglob * DECn + d;
        float cc = sf * c[cidx2] + si * tanhf(gg);
        float hh = so * tanhf(cc);
        c[cidx2] = cc;
        hall[((size_t)bglob * STEPSn + t) * DECn + d] = hh;
    }
}

// ================= logits via split-bf16 MFMA (verbatim R12) =================

__global__ __launch_bounds__(256) void k_splitA(const float* __restrict__ hall,
                                                short* __restrict__ Ah,
                                                short* __restrict__ Al) {
    int idx = blockIdx.x * 256 + threadIdx.x;
    size_t base = (size_t)idx * 4;
    float4 v = *(const float4*)(hall + base);
    float a[4] = {v.x, v.y, v.z, v.w};
    short4v h, l;
    #pragma unroll
    for (int j = 0; j < 4; ++j) {
        unsigned short hi = f2bf(a[j]);
        float lo = a[j] - __uint_as_float((unsigned)hi << 16);
        h[j] = (short)hi;
        l[j] = (short)f2bf(lo);
    }
    *(short4v*)(Ah + base) = h;
    *(short4v*)(Al + base) = l;
}

__global__ __launch_bounds__(512) void k_logits_mfma(const short* __restrict__ Ah,
                                                     const short* __restrict__ Al,
                                                     const float* __restrict__ W_out,
                                                     const float* __restrict__ b_out,
                                                     float* __restrict__ out) {
    __shared__ short Bh[48][520];
    __shared__ short Bl[48][520];
    int n0 = blockIdx.x * 48;
    int tid = threadIdx.x;
    for (int q = tid; q < 6144; q += 512) {
        int cq = q % 12, k = q / 12;
        const float* src = W_out + (size_t)k * Vn + n0 + cq * 4;
        float4 v = *(const float4*)src;
        float a[4] = {v.x, v.y, v.z, v.w};
        #pragma unroll
        for (int j = 0; j < 4; ++j) {
            unsigned short hi = f2bf(a[j]);
            float lo = a[j] - __uint_as_float((unsigned)hi << 16);
            Bh[cq * 4 + j][k] = (short)hi;
            Bl[cq * 4 + j][k] = (short)f2bf(lo);
        }
    }
    __syncthreads();
    int w = tid >> 6, l = tid & 63;
    int lr = l & 15, lk = (l >> 4) * 8;
    float bias[3];
    #pragma unroll
    for (int nt = 0; nt < 3; ++nt) bias[nt] = b_out[n0 + nt * 16 + lr];

    for (int chunk = 0; chunk < 10; ++chunk) {
        int m0 = chunk * 128 + w * 16;
        f32x4 acc[3];
        #pragma unroll
        for (int nt = 0; nt < 3; ++nt) acc[nt] = (f32x4){0.f, 0.f, 0.f, 0.f};
        #pragma unroll 2
        for (int ks = 0; ks < 16; ++ks) {
            int k0 = ks * 32;
            short8 ah = *(const short8*)(Ah + (size_t)(m0 + lr) * DECn + k0 + lk);
            short8 al = *(const short8*)(Al + (size_t)(m0 + lr) * DECn + k0 + lk);
            #pragma unroll
            for (int nt = 0; nt < 3; ++nt) {
                short8 bh = *(const short8*)&Bh[nt * 16 + lr][k0 + lk];
                short8 bl = *(const short8*)&Bl[nt * 16 + lr][k0 + lk];
                acc[nt] = __builtin_amdgcn_mfma_f32_16x16x32_bf16(ah, bh, acc[nt], 0, 0, 0);
                acc[nt] = __builtin_amdgcn_mfma_f32_16x16x32_bf16(ah, bl, acc[nt], 0, 0, 0);
                acc[nt] = __builtin_amdgcn_mfma_f32_16x16x32_bf16(al, bh, acc[nt], 0, 0, 0);
            }
        }
        #pragma unroll
        for (int nt = 0; nt < 3; ++nt) {
            int n = n0 + nt * 16 + lr;
            #pragma unroll
            for (int r = 0; r < 4; ++r) {
                int m = m0 + (l >> 4) * 4 + r;
                out[(size_t)m * Vn + n] = acc[nt][r] + bias[nt];
            }
        }
    }
}

// ================= launcher =================

extern "C" void kernel_launch(void* const* d_in, const int* in_sizes, int n_in,
                              void* d_out, int out_size, void* d_ws, size_t ws_size,
                              hipStream_t stream) {
    const float* features    = (const float*)d_in[0];
    const int*   captions    = (const int*)d_in[1];
    const int*   caption_len = (const int*)d_in[2];
    const float* emb         = (const float*)d_in[3];
    const float* W_enc       = (const float*)d_in[4];
    const float* b_enc       = (const float*)d_in[5];
    const float* W_dec       = (const float*)d_in[6];
    const float* b_dec       = (const float*)d_in[7];
    const float* W_att       = (const float*)d_in[8];
    const float* b_att       = (const float*)d_in[9];
    const float* W_h0        = (const float*)d_in[10];
    const float* b_h0        = (const float*)d_in[11];
    const float* W_c0        = (const float*)d_in[12];
    const float* b_c0        = (const float*)d_in[13];
    const float* W_ih        = (const float*)d_in[14];
    const float* b_ih        = (const float*)d_in[15];
    const float* W_hh        = (const float*)d_in[16];
    const float* b_hh        = (const float*)d_in[17];
    const float* W_out       = (const float*)d_in[18];
    const float* b_out       = (const float*)d_in[19];

    float* out = (float*)d_out;
    float* ws  = (float*)d_ws;

    unsigned short* ws_encproj = (unsigned short*)(ws + WS_ENCPROJ);
    unsigned short* ws_WT      = (unsigned short*)(ws + WS_WT);
    float* ws_ctx     = ws + WS_CTX;
    float* ws_h0      = ws + WS_H0;
    float* ws_c       = ws + WS_C;
    float* ws_hall    = ws + WS_HALL;
    float* ws_scores  = ws + WS_SCORES;
    short* ws_Ah      = (short*)(ws + WS_ENCPROJ);       // reuse enc_proj region post-loop
    short* ws_Al      = ws_Ah + (size_t)Bn * STEPSn * DECn;
    unsigned short* feat_bf = (unsigned short*)out;      // stash in unused logits region

    // ---- precompute ----
    k_feat2bf<<<dim3(Bn * Pn * ENCn / 2048), 256, 0, stream>>>(features, feat_bf);
    k_encproj_mfma<<<dim3(Pn * Bn / 128, ATTn / 128), 256, 0, stream>>>(
        features, W_enc, b_enc, ws_encproj);
    k_mean<<<dim3(Bn, ENCn / 256), 256, 0, stream>>>(features, ws_ctx);
    k_transpose_bf<<<dim3((En + ENCn + 31) / 32, Gn / 32), 256, 0, stream>>>(
        W_ih, ws_WT, Gn, En + ENCn);
    k_init_state<<<dim3(2, 16), 256, 0, stream>>>(ws_ctx, W_h0, b_h0, W_c0, b_c0,
                                                  ws_h0, ws_c);
    k_tail<<<dim3((Bn * Tn + Bn + 255) / 256), 256, 0, stream>>>(captions, caption_len, out);

    // ---- recurrence: 3 kernels per step ----
    for (int t = 0; t < STEPSn; ++t) {
        const float* hbase = (t == 0) ? ws_h0 : (ws_hall + (size_t)(t - 1) * DECn);
        int hstride = (t == 0) ? DECn : (STEPSn * DECn);
        k_scores<<<dim3(256), 256, 0, stream>>>(ws_encproj, hbase, hstride,
                                                W_dec, b_dec, W_att, b_att, ws_scores);
        k_ctxsm<<<dim3(512), 256, 0, stream>>>(feat_bf, ws_scores,
                                               out + OUT_ALPHAS, ws_ctx, t);
        k_gates<<<dim3(512), 256, 0, stream>>>(ws_WT, emb, captions, ws_ctx,
                                               hbase, hstride, b_ih, b_hh,
                                               ws_c, ws_hall, t);
    }

    // ---- logits: split A, then MFMA GEMM (overwrites feat_bf stash) ----
    k_splitA<<<dim3(Bn * STEPSn * DECn / 1024), 256, 0, stream>>>(ws_hall, ws_Ah, ws_Al);
    k_logits_mfma<<<dim3(Vn / 48), 512, 0, stream>>>(ws_Ah, ws_Al, W_out, b_out, out);
}